// Round 14
// baseline (1330.848 us; speedup 1.0000x reference)
//
#include <hip/hip_runtime.h>

typedef __attribute__((ext_vector_type(8))) short short8;
typedef __attribute__((ext_vector_type(4))) float f32x4;
typedef __attribute__((ext_vector_type(4))) unsigned int u32x4;

// ---------- helpers ----------
__device__ __forceinline__ unsigned short f2bu(float x) {
  unsigned int u = __float_as_uint(x);
  u += 0x7fffu + ((u >> 16) & 1u);
  return (unsigned short)(u >> 16);
}
__device__ __forceinline__ unsigned int pk2(float a, float b) {
  return (unsigned int)f2bu(a) | ((unsigned int)f2bu(b) << 16);
}
__device__ __forceinline__ void gload_lds16(const void* g, void* l) {
  __builtin_amdgcn_global_load_lds((const __attribute__((address_space(1))) unsigned int*)g,
                                   (__attribute__((address_space(3))) unsigned int*)l, 16, 0, 0);
}
// coherent DMA (sc0|sc1): reads from the coherence point — proven r8..r13
__device__ __forceinline__ void gload_lds16_coh(const void* g, void* l) {
  __builtin_amdgcn_global_load_lds((const __attribute__((address_space(1))) unsigned int*)g,
                                   (__attribute__((address_space(3))) unsigned int*)l, 16, 0, 17);
}
__device__ __forceinline__ void store16_coh(void* p, u32x4 v) {
  asm volatile("global_store_dwordx4 %0, %1, off sc0 sc1" :: "v"(p), "v"(v) : "memory");
}
__device__ __forceinline__ void store4u_coh(void* p, unsigned v) {
  asm volatile("global_store_dword %0, %1, off sc0 sc1" :: "v"(p), "v"(v) : "memory");
}

// ---------- cast & concat ----------
__global__ void cast_concat_kernel(const float* __restrict__ Mf,
                                   const float* __restrict__ DTf,
                                   const float* __restrict__ Df,
                                   unsigned short* __restrict__ ins) {
  size_t idx = (size_t)blockIdx.x * blockDim.x + threadIdx.x;
  size_t e0 = idx * 8;
  size_t m = e0 >> 10;
  int c = (int)(e0 & 1023);
  const float* src;
  if (c < 256)      src = Mf  + m * 256 + c;
  else if (c < 512) src = DTf + m * 256 + (c - 256);
  else              src = Df  + m * 512 + (c - 512);
  float4 f0 = reinterpret_cast<const float4*>(src)[0];
  float4 f1 = reinterpret_cast<const float4*>(src)[1];
  uint4 o;
  o.x = pk2(f0.x, f0.y); o.y = pk2(f0.z, f0.w);
  o.z = pk2(f1.x, f1.y); o.w = pk2(f1.z, f1.w);
  *reinterpret_cast<uint4*>(ins + e0) = o;
}

__global__ void cast_w_kernel(const float* __restrict__ in, unsigned short* __restrict__ out, int n8) {
  int idx = blockIdx.x * blockDim.x + threadIdx.x;
  if (idx >= n8) return;
  const float* src = in + (size_t)idx * 8;
  float4 f0 = reinterpret_cast<const float4*>(src)[0];
  float4 f1 = reinterpret_cast<const float4*>(src)[1];
  uint4 o;
  o.x = pk2(f0.x, f0.y); o.y = pk2(f0.z, f0.w);
  o.z = pk2(f1.x, f1.y); o.w = pk2(f1.z, f1.w);
  *reinterpret_cast<uint4*>(out + (size_t)idx * 8) = o;
}

// ---------- GEMM (m97 structure + XCD-chunked block swizzle, kept from r13) ----------
template <int RELU, typename TOUT>
__global__ __launch_bounds__(256) void gemm_bt_kernel(const unsigned short* __restrict__ A,
                                                      const unsigned short* __restrict__ Bt,
                                                      TOUT* __restrict__ C,
                                                      int M, int N, int K) {
  __shared__ unsigned short As[128 * 32];
  __shared__ unsigned short Bs[128 * 32];
  const int tid = threadIdx.x;
  const int l = tid & 63, w = tid >> 6;
  const int lr = l & 15, lg = l >> 4;
  const int wm = w >> 1, wn = w & 1;
  const int tiles_n = N >> 7;
  const int S = tiles_n << 3;
  const int sgrp = blockIdx.x / S, rr = blockIdx.x % S;
  const int tm = (sgrp << 3) + (rr & 7), tn = rr >> 3;
  const int bm0 = tm << 7, bn0 = tn << 7;

  f32x4 acc[4][4] = {};

  for (int kt = 0; kt < K; kt += 32) {
#pragma unroll
    for (int i = 0; i < 2; ++i) {
      int ch = tid + (i << 8);
      int row = ch >> 2, cc = ch & 3;
      const unsigned short* ga = A + (size_t)(bm0 + row) * K + kt + cc * 8;
      const unsigned short* gb = Bt + (size_t)(bn0 + row) * K + kt + cc * 8;
      unsigned short* la = As + ((size_t)((i << 8) + (w << 6))) * 8;
      unsigned short* lb = Bs + ((size_t)((i << 8) + (w << 6))) * 8;
      gload_lds16(ga, la);
      gload_lds16(gb, lb);
    }
    __syncthreads();
    short8 af[4], bf[4];
#pragma unroll
    for (int mi = 0; mi < 4; ++mi)
      af[mi] = *reinterpret_cast<const short8*>(As + (wm * 64 + mi * 16 + lr) * 32 + lg * 8);
#pragma unroll
    for (int ni = 0; ni < 4; ++ni)
      bf[ni] = *reinterpret_cast<const short8*>(Bs + (wn * 64 + ni * 16 + lr) * 32 + lg * 8);
#pragma unroll
    for (int mi = 0; mi < 4; ++mi)
#pragma unroll
      for (int ni = 0; ni < 4; ++ni)
        acc[mi][ni] = __builtin_amdgcn_mfma_f32_16x16x32_bf16(af[mi], bf[ni], acc[mi][ni], 0, 0, 0);
    __syncthreads();
  }

#pragma unroll
  for (int mi = 0; mi < 4; ++mi)
#pragma unroll
    for (int ni = 0; ni < 4; ++ni)
#pragma unroll
      for (int r = 0; r < 4; ++r) {
        int row = bm0 + wm * 64 + mi * 16 + lg * 4 + r;
        int col = bn0 + wn * 64 + ni * 16 + lr;
        float v = acc[mi][ni][r];
        if (RELU) v = fmaxf(v, 0.f);
        if constexpr (sizeof(TOUT) == 2) {
          reinterpret_cast<unsigned short*>(C)[(size_t)row * N + col] = f2bu(v);
        } else {
          C[(size_t)row * N + col] = v;
        }
      }
}

// ---------- xex scrub: invalid tags (all-zero) at coherence point, each launch ----------
__global__ void xscrub_kernel(char* xexb) {
  size_t idx = (size_t)blockIdx.x * blockDim.x + threadIdx.x;
  u32x4 z = {0, 0, 0, 0};
  store16_coh(xexb + idx * 16, z);
}

// ---------- recurrence: DUAL-STREAM tag-verified exchange ----------
// 64 blocks = 8 row-pairs (p) x 8 j-eighths (q); bid = q*8+p -> the 8 peers of
// pair p share bid%8 (XCD-local under round-robin; perf hint only).
// Streams A/B = rows 32p..+16 / 32p+16..+16. W rows [64q,64q+64) LDS-resident.
// Tile per stream/parity: [8 slices][16 rows][128B], byte = sl*2048 + i*128 +
// ((2*jc)^((i&7)<<4)). Tag: bit16 of dword at pair-pos m equals s^(m&1),
// s=(t>>1)&1. Publish = fire-and-forget sc0sc1 dwords; verify = tag check on
// the a-frags read anyway; retry = block-verdict full re-DMA (cap 64).
// Pipeline: verify_A | issue DMA_B | X/Y+G | MFMA_A | pub A | verify_B
// (counted vmcnt) | X/Y+G | MFMA_B | pub B | issue DMA_A(t+1).
#define RDCHK(TILE, ABUF, BAD)                                                \
  {                                                                           \
    BAD = 0;                                                                  \
    _Pragma("unroll") for (int kk = 0; kk < 16; ++kk) {                       \
      int off = (((kk & 1) << 6) + (lg << 4)) ^ swzA;                         \
      short8 f = *reinterpret_cast<const short8*>((TILE) + (kk >> 1) * 2048 + \
                                                  lr * 128 + off);            \
      ABUF[kk] = f;                                                           \
      u32x4 d = __builtin_bit_cast(u32x4, f);                                 \
      u32x4 xr = (d ^ e) & 0x10000u;                                          \
      BAD |= xr.x | xr.y | xr.z | xr.w;                                       \
    }                                                                         \
  }

#define DMA7(TILE, XSB)                                                       \
  _Pragma("unroll") for (int m = 0; m < 7; ++m) if ((m & 3) == wv) {          \
    int qq = rq[m];                                                           \
    gload_lds16_coh((XSB) + qq * 2048 + (size_t)l * 16, (TILE) + qq * 2048);  \
    gload_lds16_coh((XSB) + qq * 2048 + 1024 + (size_t)l * 16,                \
                    (TILE) + qq * 2048 + 1024);                               \
  }

#define VERIFY(TILE, XSB, ABUF, SS)                                           \
  {                                                                           \
    unsigned bad;                                                             \
    RDCHK(TILE, ABUF, bad);                                                   \
    volatile int* vw = vbase + (SS) * 8;                                      \
    for (int it = 0; it < 64; ++it) {                                         \
      int wb = __any(bad != 0);                                               \
      if (l == 0) vw[wv] = wb;                                                \
      __syncthreads();                                                        \
      int comb = vw[0] | vw[1] | vw[2] | vw[3];                               \
      __syncthreads();                                                        \
      if (!comb) break;                                                       \
      DMA7(TILE, XSB);                                                        \
      asm volatile("s_waitcnt vmcnt(0)" ::: "memory");                        \
      __builtin_amdgcn_sched_barrier(0);                                      \
      __syncthreads();                                                        \
      RDCHK(TILE, ABUF, bad);                                                 \
    }                                                                         \
  }

__global__ __launch_bounds__(256)
void recurrence_ds(const float* __restrict__ Whh1,
                   const float* __restrict__ x0f,
                   const float* __restrict__ G,
                   char* xexb,              // [2 parity][8 pairs][2 streams][16KB]
                   float* __restrict__ X, float* __restrict__ Y) {
  __shared__ char smem[131136];   // 64K W | 64K tiles | 64B verdict
  const int tid = threadIdx.x;
  const int l = tid & 63, wv = tid >> 6;
  const int lr = l & 15, lg = l >> 4;
  const int p = blockIdx.x & 7, q = blockIdx.x >> 3;
  const int jcolw = (wv << 4) + lr;        // 0..63 local col
  const int gcol = (q << 6) + jcolw;
  char* Wl = smem;
  char* tbase = smem + 65536;
  volatile int* vbase = (volatile int*)(smem + 131072);
  const int swzA = (lr & 7) << 4;
  const int sww = (jcolw & 7) << 4;
  const char* wbp = Wl + jcolw * 1024;
  const int prowA = p << 5, prowB = (p << 5) + 16;

  // ---- one-time: swizzled W-eighth image (rows 64q..64q+64) ----
  {
    int jj = tid >> 2;
    int kseg = (tid & 3) << 7;
    const float* wr = Whh1 + (size_t)(64 * q + jj) * 512 + kseg;
    int sw = (jj & 7) << 4;
    for (int kk = 0; kk < 128; kk += 8) {
      float4 f0 = reinterpret_cast<const float4*>(wr + kk)[0];
      float4 f1 = reinterpret_cast<const float4*>(wr + kk)[1];
      uint4 o;
      o.x = pk2(f0.x, f0.y); o.y = pk2(f0.z, f0.w);
      o.z = pk2(f1.x, f1.y); o.w = pk2(f1.z, f1.w);
      *reinterpret_cast<uint4*>(Wl + jj * 1024 + ((2 * (kseg + kk)) ^ sw)) = o;
    }
  }
  // ---- one-time: x_0 tiles for both streams (parity 0; untagged, unchecked) ----
#pragma unroll
  for (int s = 0; s < 2; ++s) {
    char* dst = tbase + (s * 2 + 0) * 16384;
#pragma unroll
    for (int c = 0; c < 4; ++c) {
      int id = tid + (c << 8);
      int row = id >> 6;
      int kc = (id & 63) << 3;
      const float* src = x0f + (size_t)((p << 5) + (s << 4) + row) * 512 + kc;
      float4 f0 = reinterpret_cast<const float4*>(src)[0];
      float4 f1 = reinterpret_cast<const float4*>(src)[1];
      uint4 o;
      o.x = pk2(f0.x, f0.y); o.y = pk2(f0.z, f0.w);
      o.z = pk2(f1.x, f1.y); o.w = pk2(f1.z, f1.w);
      int sl = kc >> 6, kp = kc & 63;
      *reinterpret_cast<uint4*>(dst + sl * 2048 + row * 128 +
                                ((2 * kp) ^ ((row & 7) << 4))) = o;
    }
  }

  float gcurA[4], gnxtA[4], gcurB[4], gnxtB[4], vsA[4], vsB[4];
  {
    const float* Gp = G + ((size_t)prowA + lg * 4) * 512 + gcol;
#pragma unroll
    for (int r = 0; r < 4; ++r) gcurA[r] = Gp[(size_t)r * 512];
    Gp = G + ((size_t)prowB + lg * 4) * 512 + gcol;
#pragma unroll
    for (int r = 0; r < 4; ++r) gcurB[r] = Gp[(size_t)r * 512];
  }
  int rq[7];
  {
    int n = 0;
    for (int qq = 0; qq < 8; ++qq)
      if (qq != q) rq[n++] = qq;
  }
  __syncthreads();

  short8 aA[16], aB[16];

#define XYDEF(T, VS, PROW)                                                    \
  if (T) {                                                                    \
    float* Xp = X + ((size_t)((T) - 1) * 256 + (PROW) + lg * 4) * 512 + gcol; \
    _Pragma("unroll") for (int r = 0; r < 4; ++r) Xp[(size_t)r * 512] = VS[r];\
    if (q == 7 && jcolw == 63)                                                \
      _Pragma("unroll") for (int r = 0; r < 4; ++r)                           \
          Y[((T) - 1) * 256 + (PROW) + lg * 4 + r] = VS[r];                   \
  }

#define GPREF(T, GN, PROW)                                                    \
  {                                                                           \
    int tn = ((T) < 255) ? (T) + 1 : (T);                                     \
    const float* Gp = G + ((size_t)tn * 256 + (PROW) + lg * 4) * 512 + gcol;  \
    _Pragma("unroll") for (int r = 0; r < 4; ++r) GN[r] = Gp[(size_t)r * 512];\
  }

#define MFMA16(ABUF, ACC)                                                     \
  _Pragma("unroll") for (int kk = 0; kk < 16; ++kk) {                         \
    short8 wf = *reinterpret_cast<const short8*>(                             \
        wbp + (((kk << 6) + (lg << 4)) ^ sww));                               \
    ACC = __builtin_amdgcn_mfma_f32_16x16x32_bf16(ABUF[kk], wf, ACC, 0, 0, 0);\
  }

#define EPI(SS, T, GCUR, GNXT, VS, ACC)                                       \
  {                                                                           \
    _Pragma("unroll") for (int r = 0; r < 4; ++r)                             \
        VS[r] = fmaxf(GCUR[r] + ACC[r], 0.f);                                 \
    _Pragma("unroll") for (int r = 0; r < 4; ++r) GCUR[r] = GNXT[r];          \
    if ((T) < 255) {                                                          \
      char* xn = tbase + ((SS) * 2 + (((T) + 1) & 1)) * 16384 + q * 2048;     \
      char* xd = xexb + ((((((T) + 1) & 1) * 8 + p) * 2 + (SS))) * 16384 +    \
                 q * 2048;                                                    \
      unsigned snx =                                                          \
          ((unsigned)((((T) + 1) >> 1) & 1) ^ (unsigned)((jcolw >> 1) & 1));  \
      _Pragma("unroll") for (int r = 0; r < 4; ++r) {                         \
        float v = VS[r];                                                      \
        float vn = __shfl_xor(v, 1);                                          \
        if (!(lr & 1)) {                                                      \
          int i = lg * 4 + r;                                                 \
          int off = i * 128 + ((2 * jcolw) ^ ((i & 7) << 4));                 \
          unsigned pv = (pk2(v, vn) & ~0x10000u) | (snx << 16);               \
          *reinterpret_cast<unsigned*>(xn + off) = pv;                        \
          store4u_coh(xd + off, pv);                                          \
        }                                                                     \
      }                                                                       \
    }                                                                         \
  }

  for (int t = 0; t < 256; ++t) {
    const unsigned sh = (unsigned)(((t >> 1) & 1) << 16);
    const u32x4 e = {sh, sh ^ 0x10000u, sh, sh ^ 0x10000u};
    char* tA = tbase + (0 * 2 + (t & 1)) * 16384;
    char* tB = tbase + (1 * 2 + (t & 1)) * 16384;
    const char* xsbA = xexb + ((((t & 1) * 8 + p) * 2 + 0)) * 16384;
    const char* xsbB = xexb + ((((t & 1) * 8 + p) * 2 + 1)) * 16384;

    // step 0: land A-DMA (issued prev-iter end) + verify A
    if (t) {
      asm volatile("s_waitcnt vmcnt(0)" ::: "memory");
      __builtin_amdgcn_sched_barrier(0);
      __syncthreads();
      VERIFY(tA, xsbA, aA, 0);
    } else {
      unsigned bad; RDCHK(tA, aA, bad); (void)bad;
    }
    // step 1: issue DMA_B(t) — flies under A's compute
    if (t) { DMA7(tB, xsbB); __builtin_amdgcn_sched_barrier(0); }
    // step 2: deferred X/Y for A(t-1) + G prefetch A(t+1)
    XYDEF(t, vsA, prowA);
    GPREF(t, gnxtA, prowA);
    // step 3: MFMA_A
    f32x4 accA = {};
    MFMA16(aA, accA);
    // step 4: epilogue + publish A(t+1)  (fire-and-forget)
    EPI(0, t, gcurA, gnxtA, vsA, accA);
    // step 5: land B-DMA (counted: skip own publish/store acks) + verify B
    if (t) {
      if (t == 255)
        asm volatile("s_waitcnt vmcnt(0)" ::: "memory");
      else
        asm volatile("s_waitcnt vmcnt(12)" ::: "memory");
      __builtin_amdgcn_sched_barrier(0);
      __syncthreads();
      VERIFY(tB, xsbB, aB, 1);
    } else {
      unsigned bad; RDCHK(tB, aB, bad); (void)bad;
    }
    // step 6: deferred X/Y for B(t-1) + G prefetch B(t+1)
    XYDEF(t, vsB, prowB);
    GPREF(t, gnxtB, prowB);
    // step 7: MFMA_B
    f32x4 accB = {};
    MFMA16(aB, accB);
    // step 8: epilogue + publish B(t+1)
    EPI(1, t, gcurB, gnxtB, vsB, accB);
    // step 9: issue DMA_A(t+1) — lands during next iter's step 0
    if (t < 255) {
      char* tAn = tbase + (0 * 2 + ((t + 1) & 1)) * 16384;
      const char* xsbAn = xexb + (((((t + 1) & 1) * 8 + p) * 2 + 0)) * 16384;
      DMA7(tAn, xsbAn);
    }
  }

  // final X/Y for t=255 (both streams)
  {
    float* Xp = X + ((size_t)255 * 256 + prowA + lg * 4) * 512 + gcol;
#pragma unroll
    for (int r = 0; r < 4; ++r) Xp[(size_t)r * 512] = vsA[r];
    Xp = X + ((size_t)255 * 256 + prowB + lg * 4) * 512 + gcol;
#pragma unroll
    for (int r = 0; r < 4; ++r) Xp[(size_t)r * 512] = vsB[r];
    if (q == 7 && jcolw == 63) {
#pragma unroll
      for (int r = 0; r < 4; ++r) {
        Y[255 * 256 + prowA + lg * 4 + r] = vsA[r];
        Y[255 * 256 + prowB + lg * 4 + r] = vsB[r];
      }
    }
  }
}
#undef RDCHK
#undef DMA7
#undef VERIFY
#undef XYDEF
#undef GPREF
#undef MFMA16
#undef EPI

// ---------- launch ----------
extern "C" void kernel_launch(void* const* d_in, const int* in_sizes, int n_in,
                              void* d_out, int out_size, void* d_ws, size_t ws_size,
                              hipStream_t stream) {
  const float* x0   = (const float*)d_in[0];
  const float* Mf   = (const float*)d_in[1];
  const float* DTf  = (const float*)d_in[2];
  const float* Df   = (const float*)d_in[3];
  const float* Wih0 = (const float*)d_in[4];
  const float* Wih1 = (const float*)d_in[6];
  const float* Whh1 = (const float*)d_in[7];

  char* ws = (char*)d_ws;
  unsigned short* ins = (unsigned short*)(ws);
  unsigned short* H   = (unsigned short*)(ws + 134217728ULL);
  unsigned short* w0b = (unsigned short*)(ws + 268435456ULL);
  unsigned short* w1b = (unsigned short*)(ws + 270532608ULL);
  char* xex           = ws + 271581184ULL;                     // 512KB: [2][8][2][16KB]
  float* G = (float*)(ws);   // aliases ins (dead after GEMM1)

  xscrub_kernel<<<128, 256, 0, stream>>>(xex);   // invalid tags each launch (replay-safe)
  cast_concat_kernel<<<32768, 256, 0, stream>>>(Mf, DTf, Df, ins);
  cast_w_kernel<<<512, 256, 0, stream>>>(Wih0, w0b, 131072);
  cast_w_kernel<<<256, 256, 0, stream>>>(Wih1, w1b, 65536);

  gemm_bt_kernel<1, unsigned short><<<(65536 / 128) * (1024 / 128), 256, 0, stream>>>(
      ins, w0b, H, 65536, 1024, 1024);
  gemm_bt_kernel<0, float><<<(65536 / 128) * (512 / 128), 256, 0, stream>>>(
      H, w1b, G, 65536, 512, 1024);

  float* X = (float*)d_out;
  float* Y = X + 33554432;
  recurrence_ds<<<64, 256, 0, stream>>>(Whh1, x0, G, xex, X, Y);
}

// Round 15
// 1083.300 us; speedup vs baseline: 1.2285x; 1.2285x over previous
//
#include <hip/hip_runtime.h>

typedef __attribute__((ext_vector_type(8))) short short8;
typedef __attribute__((ext_vector_type(4))) float f32x4;
typedef __attribute__((ext_vector_type(4))) unsigned int u32x4;

// ---------- helpers ----------
__device__ __forceinline__ unsigned short f2bu(float x) {
  unsigned int u = __float_as_uint(x);
  u += 0x7fffu + ((u >> 16) & 1u);
  return (unsigned short)(u >> 16);
}
__device__ __forceinline__ unsigned int pk2(float a, float b) {
  return (unsigned int)f2bu(a) | ((unsigned int)f2bu(b) << 16);
}
__device__ __forceinline__ void gload_lds16(const void* g, void* l) {
  __builtin_amdgcn_global_load_lds((const __attribute__((address_space(1))) unsigned int*)g,
                                   (__attribute__((address_space(3))) unsigned int*)l, 16, 0, 0);
}
// coherent DMA (sc0|sc1): reads from the coherence point — proven r8..r13
__device__ __forceinline__ void gload_lds16_coh(const void* g, void* l) {
  __builtin_amdgcn_global_load_lds((const __attribute__((address_space(1))) unsigned int*)g,
                                   (__attribute__((address_space(3))) unsigned int*)l, 16, 0, 17);
}
__device__ __forceinline__ void store16_coh(void* p, u32x4 v) {
  asm volatile("global_store_dwordx4 %0, %1, off sc0 sc1" :: "v"(p), "v"(v) : "memory");
}

// ---------- cast & concat ----------
__global__ void cast_concat_kernel(const float* __restrict__ Mf,
                                   const float* __restrict__ DTf,
                                   const float* __restrict__ Df,
                                   unsigned short* __restrict__ ins) {
  size_t idx = (size_t)blockIdx.x * blockDim.x + threadIdx.x;
  size_t e0 = idx * 8;
  size_t m = e0 >> 10;
  int c = (int)(e0 & 1023);
  const float* src;
  if (c < 256)      src = Mf  + m * 256 + c;
  else if (c < 512) src = DTf + m * 256 + (c - 256);
  else              src = Df  + m * 512 + (c - 512);
  float4 f0 = reinterpret_cast<const float4*>(src)[0];
  float4 f1 = reinterpret_cast<const float4*>(src)[1];
  uint4 o;
  o.x = pk2(f0.x, f0.y); o.y = pk2(f0.z, f0.w);
  o.z = pk2(f1.x, f1.y); o.w = pk2(f1.z, f1.w);
  *reinterpret_cast<uint4*>(ins + e0) = o;
}

__global__ void cast_w_kernel(const float* __restrict__ in, unsigned short* __restrict__ out, int n8) {
  int idx = blockIdx.x * blockDim.x + threadIdx.x;
  if (idx >= n8) return;
  const float* src = in + (size_t)idx * 8;
  float4 f0 = reinterpret_cast<const float4*>(src)[0];
  float4 f1 = reinterpret_cast<const float4*>(src)[1];
  uint4 o;
  o.x = pk2(f0.x, f0.y); o.y = pk2(f0.z, f0.w);
  o.z = pk2(f1.x, f1.y); o.w = pk2(f1.z, f1.w);
  *reinterpret_cast<uint4*>(out + (size_t)idx * 8) = o;
}

// ---------- GEMM (m97 structure + XCD-chunked block swizzle, kept from r13) ----------
template <int RELU, typename TOUT>
__global__ __launch_bounds__(256) void gemm_bt_kernel(const unsigned short* __restrict__ A,
                                                      const unsigned short* __restrict__ Bt,
                                                      TOUT* __restrict__ C,
                                                      int M, int N, int K) {
  __shared__ unsigned short As[128 * 32];
  __shared__ unsigned short Bs[128 * 32];
  const int tid = threadIdx.x;
  const int l = tid & 63, w = tid >> 6;
  const int lr = l & 15, lg = l >> 4;
  const int wm = w >> 1, wn = w & 1;
  const int tiles_n = N >> 7;
  const int S = tiles_n << 3;
  const int sgrp = blockIdx.x / S, rr = blockIdx.x % S;
  const int tm = (sgrp << 3) + (rr & 7), tn = rr >> 3;
  const int bm0 = tm << 7, bn0 = tn << 7;

  f32x4 acc[4][4] = {};

  for (int kt = 0; kt < K; kt += 32) {
#pragma unroll
    for (int i = 0; i < 2; ++i) {
      int ch = tid + (i << 8);
      int row = ch >> 2, cc = ch & 3;
      const unsigned short* ga = A + (size_t)(bm0 + row) * K + kt + cc * 8;
      const unsigned short* gb = Bt + (size_t)(bn0 + row) * K + kt + cc * 8;
      unsigned short* la = As + ((size_t)((i << 8) + (w << 6))) * 8;
      unsigned short* lb = Bs + ((size_t)((i << 8) + (w << 6))) * 8;
      gload_lds16(ga, la);
      gload_lds16(gb, lb);
    }
    __syncthreads();
    short8 af[4], bf[4];
#pragma unroll
    for (int mi = 0; mi < 4; ++mi)
      af[mi] = *reinterpret_cast<const short8*>(As + (wm * 64 + mi * 16 + lr) * 32 + lg * 8);
#pragma unroll
    for (int ni = 0; ni < 4; ++ni)
      bf[ni] = *reinterpret_cast<const short8*>(Bs + (wn * 64 + ni * 16 + lr) * 32 + lg * 8);
#pragma unroll
    for (int mi = 0; mi < 4; ++mi)
#pragma unroll
      for (int ni = 0; ni < 4; ++ni)
        acc[mi][ni] = __builtin_amdgcn_mfma_f32_16x16x32_bf16(af[mi], bf[ni], acc[mi][ni], 0, 0, 0);
    __syncthreads();
  }

#pragma unroll
  for (int mi = 0; mi < 4; ++mi)
#pragma unroll
    for (int ni = 0; ni < 4; ++ni)
#pragma unroll
      for (int r = 0; r < 4; ++r) {
        int row = bm0 + wm * 64 + mi * 16 + lg * 4 + r;
        int col = bn0 + wn * 64 + ni * 16 + lr;
        float v = acc[mi][ni][r];
        if (RELU) v = fmaxf(v, 0.f);
        if constexpr (sizeof(TOUT) == 2) {
          reinterpret_cast<unsigned short*>(C)[(size_t)row * N + col] = f2bu(v);
        } else {
          C[(size_t)row * N + col] = v;
        }
      }
}

// ---------- xex scrub: invalid tags (all-zero) at coherence point, each launch ----------
__global__ void xscrub_kernel(char* xexb) {
  size_t idx = (size_t)blockIdx.x * blockDim.x + threadIdx.x;
  u32x4 z = {0, 0, 0, 0};
  store16_coh(xexb + idx * 16, z);
}

// ---------- recurrence: tag-verified exchange, late DMA + counted-vmcnt ledger ----------
// 64 blocks = 16 groups x 4 quarters. W-quarter LDS-resident. x image per
// group/parity: [4 slices][16 rows][256B], byte = q*4096 + i*256 +
// ((2*jc)^((i&7)<<4)). Tag: bit16 of dword at pair-pos m equals s^(m&1),
// s=(t>>1)&1. Producer publishes tagged slice sc0sc1 fire-and-forget.
// Ledger (r14 fix): issue DMA(12) FIRST (still after phase-A MFMAs), then
// X/Y stores + G loads (younger), then s_waitcnt vmcnt(16): >=16 ops are
// younger than the last DMA, so <=16 outstanding proves all DMA retired —
// X-store acks and G-loads no longer serialize the step.
// Retry: per-slice verdict, re-DMA only stale slices (no polling — r13 lesson).
__global__ __launch_bounds__(256)
void recurrence_tf(const float* __restrict__ Whh1,
                   const float* __restrict__ x0f,
                   const float* __restrict__ G,
                   char* xexb,              // [2][16 groups][16KB]
                   float* __restrict__ X, float* __restrict__ Y) {
  __shared__ char smem[163840];   // [0,128K) W; [128K,144K) xls0; [144K,160K) xls1
  const int tid = threadIdx.x;
  const int l = tid & 63, wv = tid >> 6;
  const int lr = l & 15, lg = l >> 4;
  const int bid = blockIdx.x;
  const int g = ((bid & 7) << 1) | ((bid >> 3) & 1);
  const int q = bid >> 4;
  const int r0 = g << 4;
  const int jbw = wv << 5;
  char* Wl = smem;
  char* xls0 = smem + 131072;
  char* xls1 = smem + 147456;

  // ---- one-time: swizzled W-quarter image (rows 128q..128q+128) ----
  {
    int j = tid >> 1;
    int kc0 = (tid & 1) << 8;
    const float* wr = Whh1 + (size_t)(128 * q + j) * 512 + kc0;
    int sw = (j & 7) << 4;
    for (int kk = 0; kk < 256; kk += 8) {
      float4 f0 = reinterpret_cast<const float4*>(wr + kk)[0];
      float4 f1 = reinterpret_cast<const float4*>(wr + kk)[1];
      uint4 o;
      o.x = pk2(f0.x, f0.y); o.y = pk2(f0.z, f0.w);
      o.z = pk2(f1.x, f1.y); o.w = pk2(f1.z, f1.w);
      *reinterpret_cast<uint4*>(Wl + j * 1024 + ((2 * (kc0 + kk)) ^ sw)) = o;
    }
  }
  // ---- one-time: full x_0 image into xls0 (untagged; never exchanged) ----
#pragma unroll
  for (int c = 0; c < 4; ++c) {
    int id = tid + (c << 8);
    int row = id >> 6;
    int kc = (id & 63) << 3;
    int qq = kc >> 7, kp = kc & 127;
    const float* src = x0f + (size_t)(r0 + row) * 512 + kc;
    float4 f0 = reinterpret_cast<const float4*>(src)[0];
    float4 f1 = reinterpret_cast<const float4*>(src)[1];
    uint4 o;
    o.x = pk2(f0.x, f0.y); o.y = pk2(f0.z, f0.w);
    o.z = pk2(f1.x, f1.y); o.w = pk2(f1.z, f1.w);
    *reinterpret_cast<uint4*>(xls0 + qq * 4096 + row * 256 +
                              ((2 * kp) ^ ((row & 7) << 4))) = o;
  }

  // G for t=0
  float gcur[8], gnxt[8];
#pragma unroll
  for (int jt = 0; jt < 2; ++jt)
#pragma unroll
    for (int r = 0; r < 4; ++r)
      gcur[jt * 4 + r] = G[((size_t)r0 + lg * 4 + r) * 512 + q * 128 + jbw + jt * 16 + lr];
  __syncthreads();

  const int swzR = (lr & 7) << 4;
  int rq[3];
  {
    int n = 0;
    for (int qq = 0; qq < 4; ++qq)
      if (qq != q) rq[n++] = qq;
  }
  float vsave[8];
  short8 arr[12];
  unsigned mb[3];

  for (int t = 0; t < 256; ++t) {
    char* xc = (t & 1) ? xls1 : xls0;
    const unsigned sh = (unsigned)(((t >> 1) & 1) << 16);
    const u32x4 e = {sh, sh ^ 0x10000u, sh, sh ^ 0x10000u};

    // ---- phase A: own-quarter MFMAs (local LDS — gives producers slack) ----
    f32x4 acc[2] = {};
    {
      short8 ao[4];
#pragma unroll
      for (int kp = 0; kp < 4; ++kp)
        ao[kp] = *reinterpret_cast<const short8*>(
            xc + q * 4096 + lr * 256 + ((kp * 64 + lg * 16) ^ swzR));
#pragma unroll
      for (int jt = 0; jt < 2; ++jt) {
        int jl = jbw + jt * 16 + lr;
        const char* wb = Wl + jl * 1024;
        int swj = (jl & 7) << 4;
#pragma unroll
        for (int kp = 0; kp < 4; ++kp) {
          short8 wf = *reinterpret_cast<const short8*>(
              wb + (((q * 4 + kp) * 64 + lg * 16) ^ swj));
          acc[jt] = __builtin_amdgcn_mfma_f32_16x16x32_bf16(ao[kp], wf, acc[jt], 0, 0, 0);
        }
      }
    }

    // ---- phase B: late DMA (oldest), then X/Y+G (younger), counted wait ----
#define READCHECK()                                                           \
  {                                                                           \
    mb[0] = mb[1] = mb[2] = 0;                                                \
    _Pragma("unroll") for (int m = 0; m < 3; ++m) {                           \
      int qq = rq[m];                                                         \
      _Pragma("unroll") for (int kp = 0; kp < 4; ++kp) {                      \
        short8 f = *reinterpret_cast<const short8*>(                          \
            xc + qq * 4096 + lr * 256 + ((kp * 64 + lg * 16) ^ swzR));        \
        arr[m * 4 + kp] = f;                                                  \
        u32x4 d = __builtin_bit_cast(u32x4, f);                               \
        u32x4 xr = (d ^ e) & 0x10000u;                                        \
        mb[m] |= xr.x | xr.y | xr.z | xr.w;                                   \
      }                                                                       \
    }                                                                         \
  }
#define PHASE0()                                                              \
  {                                                                           \
    if (t) {                                                                  \
      float* Xp = X + ((size_t)(t - 1) * 256 + r0) * 512 + q * 128;           \
      _Pragma("unroll") for (int jt = 0; jt < 2; ++jt)                        \
          _Pragma("unroll") for (int r = 0; r < 4; ++r)                       \
              Xp[(size_t)(lg * 4 + r) * 512 + jbw + jt * 16 + lr] =           \
                  vsave[jt * 4 + r];                                          \
      if (q == 3 && wv == 3 && lr == 15)                                      \
        _Pragma("unroll") for (int r = 0; r < 4; ++r)                         \
            Y[(t - 1) * 256 + r0 + lg * 4 + r] = vsave[4 + r];                \
    }                                                                         \
    int tn = (t < 255) ? t + 1 : t;                                           \
    const float* Gn = G + ((size_t)tn * 256 + r0) * 512 + q * 128;            \
    _Pragma("unroll") for (int jt = 0; jt < 2; ++jt)                          \
        _Pragma("unroll") for (int r = 0; r < 4; ++r)                         \
            gnxt[jt * 4 + r] = Gn[(size_t)(lg * 4 + r) * 512 + jbw + jt * 16 + lr]; \
  }
    if (t) {
      const char* xsb = xexb + (((t & 1) * 16 + g) * 16384);
      // DMA first — becomes the oldest VMEM in flight
#pragma unroll
      for (int m = 0; m < 3; ++m)
        gload_lds16_coh(xsb + rq[m] * 4096 + wv * 1024 + (size_t)l * 16,
                        xc + rq[m] * 4096 + wv * 1024);
      __builtin_amdgcn_sched_barrier(0);
      // X/Y stores + G loads — younger than the DMA (>=16 ops)
      PHASE0();
      __builtin_amdgcn_sched_barrier(0);
      // counted wait: <=16 outstanding => all 12 DMA retired (oldest-first)
      asm volatile("s_waitcnt vmcnt(16)" ::: "memory");
      __builtin_amdgcn_sched_barrier(0);
      __syncthreads();
      READCHECK();
      volatile int* vw = (volatile int*)(xc + q * 4096);  // own-slice row0 (phase-A reads done)
      for (int it = 0; it < 64; ++it) {
        unsigned wm = (__any(mb[0]) ? 1u : 0u) | (__any(mb[1]) ? 2u : 0u) |
                      (__any(mb[2]) ? 4u : 0u);
        if (l == 0) vw[wv] = (int)wm;
        __syncthreads();
        unsigned comb = (unsigned)(vw[0] | vw[1] | vw[2] | vw[3]) & 7u;
        if (!comb) break;
        // re-DMA only the stale slices
#pragma unroll
        for (int m = 0; m < 3; ++m)
          if (comb & (1u << m))
            gload_lds16_coh(xsb + rq[m] * 4096 + wv * 1024 + (size_t)l * 16,
                            xc + rq[m] * 4096 + wv * 1024);
        asm volatile("s_waitcnt vmcnt(0)" ::: "memory");
        __builtin_amdgcn_sched_barrier(0);
        __syncthreads();
        READCHECK();
      }
    } else {
      PHASE0();
      READCHECK();   // all-local x0, no verification needed
    }
#undef PHASE0
#undef READCHECK

    // ---- phase C: remote-quarter MFMAs from verified frags ----
#pragma unroll
    for (int m = 0; m < 3; ++m) {
      int qq = rq[m];
#pragma unroll
      for (int jt = 0; jt < 2; ++jt) {
        int jl = jbw + jt * 16 + lr;
        const char* wb = Wl + jl * 1024;
        int swj = (jl & 7) << 4;
#pragma unroll
        for (int kp = 0; kp < 4; ++kp) {
          short8 wf = *reinterpret_cast<const short8*>(
              wb + (((qq * 4 + kp) * 64 + lg * 16) ^ swj));
          acc[jt] = __builtin_amdgcn_mfma_f32_16x16x32_bf16(arr[m * 4 + kp], wf, acc[jt], 0, 0, 0);
        }
      }
    }

    // ---- phase D: epilogue ----
#pragma unroll
    for (int jt = 0; jt < 2; ++jt)
#pragma unroll
      for (int r = 0; r < 4; ++r)
        vsave[jt * 4 + r] = fmaxf(gcur[jt * 4 + r] + acc[jt][r], 0.f);
#pragma unroll
    for (int ee = 0; ee < 8; ++ee) gcur[ee] = gnxt[ee];

    if (t < 255) {
      char* xn = (t & 1) ? xls0 : xls1;
      const unsigned snext = (unsigned)(((t + 1) >> 1) & 1);
#pragma unroll
      for (int jt = 0; jt < 2; ++jt)
#pragma unroll
        for (int r = 0; r < 4; ++r) {
          float v = vsave[jt * 4 + r];
          float vn = __shfl_xor(v, 1);
          if (!(lr & 1)) {
            int i = lg * 4 + r;
            int jc = jbw + jt * 16 + lr;
            unsigned pv = pk2(v, vn);
            pv = (pv & ~0x10000u) | ((snext ^ (unsigned)((jc >> 1) & 1)) << 16);
            *reinterpret_cast<unsigned int*>(
                xn + q * 4096 + i * 256 + ((2 * jc) ^ ((i & 7) << 4))) = pv;
          }
        }
      // publish own slice: coalesced, fire-and-forget (tag IS the flag)
      __syncthreads();
      char* xd = xexb + ((((t + 1) & 1) * 16 + g) * 16384) + q * 4096;
      u32x4 val = *reinterpret_cast<const u32x4*>(xn + q * 4096 + tid * 16);
      store16_coh(xd + tid * 16, val);
    }
  }

  // final X/Y for t=255
  {
    float* Xp = X + ((size_t)255 * 256 + r0) * 512 + q * 128;
#pragma unroll
    for (int jt = 0; jt < 2; ++jt)
#pragma unroll
      for (int r = 0; r < 4; ++r)
        Xp[(size_t)(lg * 4 + r) * 512 + jbw + jt * 16 + lr] = vsave[jt * 4 + r];
    if (q == 3 && wv == 3 && lr == 15)
#pragma unroll
      for (int r = 0; r < 4; ++r)
        Y[255 * 256 + r0 + lg * 4 + r] = vsave[4 + r];
  }
}

// ---------- launch ----------
extern "C" void kernel_launch(void* const* d_in, const int* in_sizes, int n_in,
                              void* d_out, int out_size, void* d_ws, size_t ws_size,
                              hipStream_t stream) {
  const float* x0   = (const float*)d_in[0];
  const float* Mf   = (const float*)d_in[1];
  const float* DTf  = (const float*)d_in[2];
  const float* Df   = (const float*)d_in[3];
  const float* Wih0 = (const float*)d_in[4];
  const float* Wih1 = (const float*)d_in[6];
  const float* Whh1 = (const float*)d_in[7];

  char* ws = (char*)d_ws;
  unsigned short* ins = (unsigned short*)(ws);
  unsigned short* H   = (unsigned short*)(ws + 134217728ULL);
  unsigned short* w0b = (unsigned short*)(ws + 268435456ULL);
  unsigned short* w1b = (unsigned short*)(ws + 270532608ULL);
  char* xex           = ws + 271581184ULL;                     // 512KB: [2][16][16KB]
  float* G = (float*)(ws);   // aliases ins (dead after GEMM1)

  xscrub_kernel<<<128, 256, 0, stream>>>(xex);   // invalid tags each launch (replay-safe)
  cast_concat_kernel<<<32768, 256, 0, stream>>>(Mf, DTf, Df, ins);
  cast_w_kernel<<<512, 256, 0, stream>>>(Wih0, w0b, 131072);
  cast_w_kernel<<<256, 256, 0, stream>>>(Wih1, w1b, 65536);

  gemm_bt_kernel<1, unsigned short><<<(65536 / 128) * (1024 / 128), 256, 0, stream>>>(
      ins, w0b, H, 65536, 1024, 1024);
  gemm_bt_kernel<0, float><<<(65536 / 128) * (512 / 128), 256, 0, stream>>>(
      H, w1b, G, 65536, 512, 1024);

  float* X = (float*)d_out;
  float* Y = X + 33554432;
  recurrence_tf<<<64, 256, 0, stream>>>(Whh1, x0, G, xex, X, Y);
}

// Round 16
// 959.776 us; speedup vs baseline: 1.3866x; 1.1287x over previous
//
#include <hip/hip_runtime.h>

typedef __attribute__((ext_vector_type(8))) short short8;
typedef __attribute__((ext_vector_type(4))) float f32x4;
typedef __attribute__((ext_vector_type(4))) unsigned int u32x4;

// ---------- helpers ----------
__device__ __forceinline__ unsigned short f2bu(float x) {
  unsigned int u = __float_as_uint(x);
  u += 0x7fffu + ((u >> 16) & 1u);
  return (unsigned short)(u >> 16);
}
__device__ __forceinline__ unsigned int pk2(float a, float b) {
  return (unsigned int)f2bu(a) | ((unsigned int)f2bu(b) << 16);
}
__device__ __forceinline__ void gload_lds16(const void* g, void* l) {
  __builtin_amdgcn_global_load_lds((const __attribute__((address_space(1))) unsigned int*)g,
                                   (__attribute__((address_space(3))) unsigned int*)l, 16, 0, 0);
}
// coherent DMA (sc0|sc1): reads from the coherence point — proven r8..r13
__device__ __forceinline__ void gload_lds16_coh(const void* g, void* l) {
  __builtin_amdgcn_global_load_lds((const __attribute__((address_space(1))) unsigned int*)g,
                                   (__attribute__((address_space(3))) unsigned int*)l, 16, 0, 17);
}
__device__ __forceinline__ void store16_coh(void* p, u32x4 v) {
  asm volatile("global_store_dwordx4 %0, %1, off sc0 sc1" :: "v"(p), "v"(v) : "memory");
}

// ---------- cast & concat ----------
__global__ void cast_concat_kernel(const float* __restrict__ Mf,
                                   const float* __restrict__ DTf,
                                   const float* __restrict__ Df,
                                   unsigned short* __restrict__ ins) {
  size_t idx = (size_t)blockIdx.x * blockDim.x + threadIdx.x;
  size_t e0 = idx * 8;
  size_t m = e0 >> 10;
  int c = (int)(e0 & 1023);
  const float* src;
  if (c < 256)      src = Mf  + m * 256 + c;
  else if (c < 512) src = DTf + m * 256 + (c - 256);
  else              src = Df  + m * 512 + (c - 512);
  float4 f0 = reinterpret_cast<const float4*>(src)[0];
  float4 f1 = reinterpret_cast<const float4*>(src)[1];
  uint4 o;
  o.x = pk2(f0.x, f0.y); o.y = pk2(f0.z, f0.w);
  o.z = pk2(f1.x, f1.y); o.w = pk2(f1.z, f1.w);
  *reinterpret_cast<uint4*>(ins + e0) = o;
}

__global__ void cast_w_kernel(const float* __restrict__ in, unsigned short* __restrict__ out, int n8) {
  int idx = blockIdx.x * blockDim.x + threadIdx.x;
  if (idx >= n8) return;
  const float* src = in + (size_t)idx * 8;
  float4 f0 = reinterpret_cast<const float4*>(src)[0];
  float4 f1 = reinterpret_cast<const float4*>(src)[1];
  uint4 o;
  o.x = pk2(f0.x, f0.y); o.y = pk2(f0.z, f0.w);
  o.z = pk2(f1.x, f1.y); o.w = pk2(f1.z, f1.w);
  *reinterpret_cast<uint4*>(out + (size_t)idx * 8) = o;
}

// ---------- GEMM: 256x256 tile, BK=64, 4-phase/K-tile deep pipeline ----------
// 512 threads = 8 waves (2M x 4N); per-wave output 128x64 (acc[8][4]).
// LDS 128KB: 2 bufs x (A[256][64] + B[256][64]) bf16. Chunk-XOR swizzle
// (chunk ^= row&7) on both sides: pre-swizzled global src for linear
// global_load_lds dest + swizzled ds_read (rule #21).
// Per K-tile kt: p0{read A-mh0(8)+B(8), MFMA(m0,n0)} p1{stage Amh0+Bh0 for
// kt+2, MFMA(m0,n1)} p2{read A-mh1, stage Bh1, MFMA(m1,n0)} p3{stage Amh1,
// MFMA(m1,n1), vmcnt(8|0), barrier}. Stages target regions freed by the
// previous phase's end-barrier (all waves' reads retired via lgkmcnt(0)).
// Ledger: at tile-end, kt+2's 8 loads are the only ones younger than kt+1's
// -> vmcnt(8) proves kt+1 landed; tail uses vmcnt(0).
template <int RELU, typename TOUT>
__global__ __launch_bounds__(512, 2) void gemm256_kernel(
    const unsigned short* __restrict__ A, const unsigned short* __restrict__ Bt,
    TOUT* __restrict__ C, int M, int N, int K) {
  __shared__ unsigned short lds[2][2][16384];
  const int tid = threadIdx.x;
  const int l = tid & 63, w = tid >> 6;
  const int lr = l & 15, lg = l >> 4;
  const int wm = w >> 2, wn = w & 3;
  const int tiles_n = N >> 8;
  const int S = tiles_n << 3;
  const int sgrp = blockIdx.x / S, rr = blockIdx.x % S;
  const int tm = (sgrp << 3) + (rr & 7), tn = rr >> 3;   // XCD A-panel swizzle
  const int bm0 = tm << 8, bn0 = tn << 8;
  const int NT = K >> 6;
  const unsigned short* Ab = A + (size_t)bm0 * K;
  const unsigned short* Bb = Bt + (size_t)bn0 * K;
  const int srow = l >> 3;                   // row within 8-row wave-chunk
  const int scol = ((l & 7) ^ srow) << 3;    // pre-swizzled src col (elements)
  const int swz = lr & 7;

  f32x4 acc[8][4] = {};

#define STG8(SRC, R0, LDSS, KT2)                                              \
  gload_lds16((SRC) + (size_t)((R0) + srow) * K + ((KT2) << 6) + scol,        \
              (LDSS) + (R0) * 64)

  // prologue: stage tiles 0 and 1 (8 wave-loads each)
#pragma unroll
  for (int t0 = 0; t0 < 2; ++t0) {
    unsigned short* As_ = lds[t0][0];
    unsigned short* Bs_ = lds[t0][1];
    STG8(Ab, (w << 3), As_, t0);
    STG8(Ab, 128 + (w << 3), As_, t0);
    STG8(Ab, 64 + (w << 3), As_, t0);
    STG8(Ab, 192 + (w << 3), As_, t0);
    STG8(Bb, (w << 3), Bs_, t0);
    STG8(Bb, 64 + (w << 3), Bs_, t0);
    STG8(Bb, 128 + (w << 3), Bs_, t0);
    STG8(Bb, 192 + (w << 3), Bs_, t0);
  }
  asm volatile("s_waitcnt vmcnt(8)" ::: "memory");   // tile0's 8 are the oldest
  __builtin_amdgcn_s_barrier();

  for (int kt = 0; kt < NT; ++kt) {
    const unsigned short* Asd = lds[kt & 1][0];
    const unsigned short* Bsd = lds[kt & 1][1];
    unsigned short* Asn = lds[kt & 1][0];
    unsigned short* Bsn = lds[kt & 1][1];
    const int kt2 = kt + 2;
    const bool dostg = kt2 < NT;

    short8 a[4][2], b[4][2];
    // ---- p0: read A[mh0] + all B; MFMA (m0, n0) ----
#pragma unroll
    for (int i = 0; i < 4; ++i) {
      int row = wm * 128 + i * 16 + lr;
#pragma unroll
      for (int s = 0; s < 2; ++s)
        a[i][s] = *reinterpret_cast<const short8*>(
            Asd + row * 64 + ((((s << 2) + lg) ^ swz) << 3));
    }
#pragma unroll
    for (int ni = 0; ni < 4; ++ni) {
      int row = wn * 64 + ni * 16 + lr;
#pragma unroll
      for (int s = 0; s < 2; ++s)
        b[ni][s] = *reinterpret_cast<const short8*>(
            Bsd + row * 64 + ((((s << 2) + lg) ^ swz) << 3));
    }
    asm volatile("s_waitcnt lgkmcnt(0)" ::: "memory");
    __builtin_amdgcn_sched_barrier(0);
    __builtin_amdgcn_s_setprio(1);
#pragma unroll
    for (int ni = 0; ni < 2; ++ni)
#pragma unroll
      for (int i = 0; i < 4; ++i)
#pragma unroll
        for (int s = 0; s < 2; ++s)
          acc[i][ni] = __builtin_amdgcn_mfma_f32_16x16x32_bf16(a[i][s], b[ni][s], acc[i][ni], 0, 0, 0);
    __builtin_amdgcn_s_setprio(0);
    __builtin_amdgcn_s_barrier();   // A-mh0 + B regions free block-wide

    // ---- p1: stage A-mh0 + B-h0 (kt+2); MFMA (m0, n1) ----
    if (dostg) {
      STG8(Ab, (w << 3), Asn, kt2);
      STG8(Ab, 128 + (w << 3), Asn, kt2);
      STG8(Bb, (w << 3), Bsn, kt2);
      STG8(Bb, 64 + (w << 3), Bsn, kt2);
    }
    __builtin_amdgcn_s_setprio(1);
#pragma unroll
    for (int ni = 2; ni < 4; ++ni)
#pragma unroll
      for (int i = 0; i < 4; ++i)
#pragma unroll
        for (int s = 0; s < 2; ++s)
          acc[i][ni] = __builtin_amdgcn_mfma_f32_16x16x32_bf16(a[i][s], b[ni][s], acc[i][ni], 0, 0, 0);
    __builtin_amdgcn_s_setprio(0);
    __builtin_amdgcn_s_barrier();

    // ---- p2: read A[mh1]; stage B-h1; MFMA (m1, n0) ----
#pragma unroll
    for (int i = 0; i < 4; ++i) {
      int row = wm * 128 + 64 + i * 16 + lr;
#pragma unroll
      for (int s = 0; s < 2; ++s)
        a[i][s] = *reinterpret_cast<const short8*>(
            Asd + row * 64 + ((((s << 2) + lg) ^ swz) << 3));
    }
    if (dostg) {
      STG8(Bb, 128 + (w << 3), Bsn, kt2);
      STG8(Bb, 192 + (w << 3), Bsn, kt2);
    }
    asm volatile("s_waitcnt lgkmcnt(0)" ::: "memory");
    __builtin_amdgcn_sched_barrier(0);
    __builtin_amdgcn_s_setprio(1);
#pragma unroll
    for (int ni = 0; ni < 2; ++ni)
#pragma unroll
      for (int i = 0; i < 4; ++i)
#pragma unroll
        for (int s = 0; s < 2; ++s)
          acc[4 + i][ni] = __builtin_amdgcn_mfma_f32_16x16x32_bf16(a[i][s], b[ni][s], acc[4 + i][ni], 0, 0, 0);
    __builtin_amdgcn_s_setprio(0);
    __builtin_amdgcn_s_barrier();   // A-mh1 region free

    // ---- p3: stage A-mh1; MFMA (m1, n1); tile-end counted wait ----
    if (dostg) {
      STG8(Ab, 64 + (w << 3), Asn, kt2);
      STG8(Ab, 192 + (w << 3), Asn, kt2);
    }
    __builtin_amdgcn_s_setprio(1);
#pragma unroll
    for (int ni = 2; ni < 4; ++ni)
#pragma unroll
      for (int i = 0; i < 4; ++i)
#pragma unroll
        for (int s = 0; s < 2; ++s)
          acc[4 + i][ni] = __builtin_amdgcn_mfma_f32_16x16x32_bf16(a[i][s], b[ni][s], acc[4 + i][ni], 0, 0, 0);
    __builtin_amdgcn_s_setprio(0);
    if (kt + 2 < NT)
      asm volatile("s_waitcnt vmcnt(8)" ::: "memory");   // kt+1's loads landed
    else
      asm volatile("s_waitcnt vmcnt(0)" ::: "memory");   // tail: drain
    __builtin_amdgcn_s_barrier();
  }
#undef STG8

  // ---- epilogue ----
#pragma unroll
  for (int mi = 0; mi < 8; ++mi)
#pragma unroll
    for (int ni = 0; ni < 4; ++ni)
#pragma unroll
      for (int r = 0; r < 4; ++r) {
        int row = bm0 + wm * 128 + mi * 16 + lg * 4 + r;
        int col = bn0 + wn * 64 + ni * 16 + lr;
        float v = acc[mi][ni][r];
        if (RELU) v = fmaxf(v, 0.f);
        if constexpr (sizeof(TOUT) == 2) {
          reinterpret_cast<unsigned short*>(C)[(size_t)row * N + col] = f2bu(v);
        } else {
          C[(size_t)row * N + col] = v;
        }
      }
}

// ---------- xex scrub: invalid tags (all-zero) at coherence point, each launch ----------
__global__ void xscrub_kernel(char* xexb) {
  size_t idx = (size_t)blockIdx.x * blockDim.x + threadIdx.x;
  u32x4 z = {0, 0, 0, 0};
  store16_coh(xexb + idx * 16, z);
}

// ---------- recurrence: r12 exact (tag-verified, late DMA, full re-DMA retry) ----------
__global__ __launch_bounds__(256)
void recurrence_tf(const float* __restrict__ Whh1,
                   const float* __restrict__ x0f,
                   const float* __restrict__ G,
                   char* xexb,              // [2][16 groups][16KB]
                   float* __restrict__ X, float* __restrict__ Y) {
  __shared__ char smem[163840];
  const int tid = threadIdx.x;
  const int l = tid & 63, wv = tid >> 6;
  const int lr = l & 15, lg = l >> 4;
  const int bid = blockIdx.x;
  const int g = ((bid & 7) << 1) | ((bid >> 3) & 1);
  const int q = bid >> 4;
  const int r0 = g << 4;
  const int jbw = wv << 5;
  char* Wl = smem;
  char* xls0 = smem + 131072;
  char* xls1 = smem + 147456;

  {
    int j = tid >> 1;
    int kc0 = (tid & 1) << 8;
    const float* wr = Whh1 + (size_t)(128 * q + j) * 512 + kc0;
    int sw = (j & 7) << 4;
    for (int kk = 0; kk < 256; kk += 8) {
      float4 f0 = reinterpret_cast<const float4*>(wr + kk)[0];
      float4 f1 = reinterpret_cast<const float4*>(wr + kk)[1];
      uint4 o;
      o.x = pk2(f0.x, f0.y); o.y = pk2(f0.z, f0.w);
      o.z = pk2(f1.x, f1.y); o.w = pk2(f1.z, f1.w);
      *reinterpret_cast<uint4*>(Wl + j * 1024 + ((2 * (kc0 + kk)) ^ sw)) = o;
    }
  }
#pragma unroll
  for (int c = 0; c < 4; ++c) {
    int id = tid + (c << 8);
    int row = id >> 6;
    int kc = (id & 63) << 3;
    int qq = kc >> 7, kp = kc & 127;
    const float* src = x0f + (size_t)(r0 + row) * 512 + kc;
    float4 f0 = reinterpret_cast<const float4*>(src)[0];
    float4 f1 = reinterpret_cast<const float4*>(src)[1];
    uint4 o;
    o.x = pk2(f0.x, f0.y); o.y = pk2(f0.z, f0.w);
    o.z = pk2(f1.x, f1.y); o.w = pk2(f1.z, f1.w);
    *reinterpret_cast<uint4*>(xls0 + qq * 4096 + row * 256 +
                              ((2 * kp) ^ ((row & 7) << 4))) = o;
  }

  float gcur[8], gnxt[8];
#pragma unroll
  for (int jt = 0; jt < 2; ++jt)
#pragma unroll
    for (int r = 0; r < 4; ++r)
      gcur[jt * 4 + r] = G[((size_t)r0 + lg * 4 + r) * 512 + q * 128 + jbw + jt * 16 + lr];
  __syncthreads();

  const int swzR = (lr & 7) << 4;
  int rq[3];
  {
    int n = 0;
    for (int qq = 0; qq < 4; ++qq)
      if (qq != q) rq[n++] = qq;
  }
  float vsave[8];
  short8 arr[12];
  int ep = 1;

  for (int t = 0; t < 256; ++t) {
    char* xc = (t & 1) ? xls1 : xls0;
    const unsigned sh = (unsigned)(((t >> 1) & 1) << 16);
    const u32x4 e = {sh, sh ^ 0x10000u, sh, sh ^ 0x10000u};

    // phase 0: deferred X/Y for t-1, G prefetch for t+1
    if (t) {
      float* Xp = X + ((size_t)(t - 1) * 256 + r0) * 512 + q * 128;
#pragma unroll
      for (int jt = 0; jt < 2; ++jt)
#pragma unroll
        for (int r = 0; r < 4; ++r)
          Xp[(size_t)(lg * 4 + r) * 512 + jbw + jt * 16 + lr] = vsave[jt * 4 + r];
      if (q == 3 && wv == 3 && lr == 15)
#pragma unroll
        for (int r = 0; r < 4; ++r)
          Y[(t - 1) * 256 + r0 + lg * 4 + r] = vsave[4 + r];
    }
    {
      int tn = (t < 255) ? t + 1 : t;
      const float* Gn = G + ((size_t)tn * 256 + r0) * 512 + q * 128;
#pragma unroll
      for (int jt = 0; jt < 2; ++jt)
#pragma unroll
        for (int r = 0; r < 4; ++r)
          gnxt[jt * 4 + r] = Gn[(size_t)(lg * 4 + r) * 512 + jbw + jt * 16 + lr];
    }

    // phase A: own-quarter MFMAs
    f32x4 acc[2] = {};
    {
      short8 ao[4];
#pragma unroll
      for (int kp = 0; kp < 4; ++kp)
        ao[kp] = *reinterpret_cast<const short8*>(
            xc + q * 4096 + lr * 256 + ((kp * 64 + lg * 16) ^ swzR));
#pragma unroll
      for (int jt = 0; jt < 2; ++jt) {
        int jl = jbw + jt * 16 + lr;
        const char* wb = Wl + jl * 1024;
        int swj = (jl & 7) << 4;
#pragma unroll
        for (int kp = 0; kp < 4; ++kp) {
          short8 wf = *reinterpret_cast<const short8*>(
              wb + (((q * 4 + kp) * 64 + lg * 16) ^ swj));
          acc[jt] = __builtin_amdgcn_mfma_f32_16x16x32_bf16(ao[kp], wf, acc[jt], 0, 0, 0);
        }
      }
    }

    // phase B: LATE DMA, land, tag-verify (retry net)
    unsigned mybad = 0;
#define READCHECK()                                                           \
  {                                                                           \
    mybad = 0;                                                                \
    _Pragma("unroll") for (int m = 0; m < 3; ++m) {                           \
      int qq = rq[m];                                                         \
      _Pragma("unroll") for (int kp = 0; kp < 4; ++kp) {                      \
        short8 f = *reinterpret_cast<const short8*>(                          \
            xc + qq * 4096 + lr * 256 + ((kp * 64 + lg * 16) ^ swzR));        \
        arr[m * 4 + kp] = f;                                                  \
        u32x4 d = __builtin_bit_cast(u32x4, f);                               \
        u32x4 xr = (d ^ e) & 0x10000u;                                        \
        mybad |= xr.x | xr.y | xr.z | xr.w;                                   \
      }                                                                       \
    }                                                                         \
  }
    if (t) {
      const char* xsb = xexb + (((t & 1) * 16 + g) * 16384);
#pragma unroll
      for (int m = 0; m < 3; ++m)
        gload_lds16_coh(xsb + rq[m] * 4096 + wv * 1024 + (size_t)l * 16,
                        xc + rq[m] * 4096 + wv * 1024);
      asm volatile("s_waitcnt vmcnt(0)" ::: "memory");
      __builtin_amdgcn_sched_barrier(0);
      __syncthreads();
      READCHECK();
      int* badw = (int*)(xc + q * 4096);
      for (int it = 0; it < 64; ++it) {
        if (__any(mybad != 0)) { if (l == 0) *badw = ep; }
        __syncthreads();
        bool bad = (*badw == ep);
        ++ep;
        if (!bad) break;
#pragma unroll
        for (int m = 0; m < 3; ++m)
          gload_lds16_coh(xsb + rq[m] * 4096 + wv * 1024 + (size_t)l * 16,
                          xc + rq[m] * 4096 + wv * 1024);
        asm volatile("s_waitcnt vmcnt(0)" ::: "memory");
        __builtin_amdgcn_sched_barrier(0);
        __syncthreads();
        READCHECK();
      }
    } else {
      READCHECK();
    }
#undef READCHECK

    // phase C: remote-quarter MFMAs
#pragma unroll
    for (int m = 0; m < 3; ++m) {
      int qq = rq[m];
#pragma unroll
      for (int jt = 0; jt < 2; ++jt) {
        int jl = jbw + jt * 16 + lr;
        const char* wb = Wl + jl * 1024;
        int swj = (jl & 7) << 4;
#pragma unroll
        for (int kp = 0; kp < 4; ++kp) {
          short8 wf = *reinterpret_cast<const short8*>(
              wb + (((qq * 4 + kp) * 64 + lg * 16) ^ swj));
          acc[jt] = __builtin_amdgcn_mfma_f32_16x16x32_bf16(arr[m * 4 + kp], wf, acc[jt], 0, 0, 0);
        }
      }
    }

    // phase D: epilogue
#pragma unroll
    for (int jt = 0; jt < 2; ++jt)
#pragma unroll
      for (int r = 0; r < 4; ++r)
        vsave[jt * 4 + r] = fmaxf(gcur[jt * 4 + r] + acc[jt][r], 0.f);
#pragma unroll
    for (int ee = 0; ee < 8; ++ee) gcur[ee] = gnxt[ee];

    if (t < 255) {
      char* xn = (t & 1) ? xls0 : xls1;
      const unsigned snext = (unsigned)(((t + 1) >> 1) & 1);
#pragma unroll
      for (int jt = 0; jt < 2; ++jt)
#pragma unroll
        for (int r = 0; r < 4; ++r) {
          float v = vsave[jt * 4 + r];
          float vn = __shfl_xor(v, 1);
          if (!(lr & 1)) {
            int i = lg * 4 + r;
            int jc = jbw + jt * 16 + lr;
            unsigned pv = pk2(v, vn);
            pv = (pv & ~0x10000u) | ((snext ^ (unsigned)((jc >> 1) & 1)) << 16);
            *reinterpret_cast<unsigned int*>(
                xn + q * 4096 + i * 256 + ((2 * jc) ^ ((i & 7) << 4))) = pv;
          }
        }
      __syncthreads();
      char* xd = xexb + ((((t + 1) & 1) * 16 + g) * 16384) + q * 4096;
      u32x4 val = *reinterpret_cast<const u32x4*>(xn + q * 4096 + tid * 16);
      store16_coh(xd + tid * 16, val);
    }
  }

  {
    float* Xp = X + ((size_t)255 * 256 + r0) * 512 + q * 128;
#pragma unroll
    for (int jt = 0; jt < 2; ++jt)
#pragma unroll
      for (int r = 0; r < 4; ++r)
        Xp[(size_t)(lg * 4 + r) * 512 + jbw + jt * 16 + lr] = vsave[jt * 4 + r];
    if (q == 3 && wv == 3 && lr == 15)
#pragma unroll
      for (int r = 0; r < 4; ++r)
        Y[255 * 256 + r0 + lg * 4 + r] = vsave[4 + r];
  }
}

// ---------- launch ----------
extern "C" void kernel_launch(void* const* d_in, const int* in_sizes, int n_in,
                              void* d_out, int out_size, void* d_ws, size_t ws_size,
                              hipStream_t stream) {
  const float* x0   = (const float*)d_in[0];
  const float* Mf   = (const float*)d_in[1];
  const float* DTf  = (const float*)d_in[2];
  const float* Df   = (const float*)d_in[3];
  const float* Wih0 = (const float*)d_in[4];
  const float* Wih1 = (const float*)d_in[6];
  const float* Whh1 = (const float*)d_in[7];

  char* ws = (char*)d_ws;
  unsigned short* ins = (unsigned short*)(ws);
  unsigned short* H   = (unsigned short*)(ws + 134217728ULL);
  unsigned short* w0b = (unsigned short*)(ws + 268435456ULL);
  unsigned short* w1b = (unsigned short*)(ws + 270532608ULL);
  char* xex           = ws + 271581184ULL;                     // 512KB: [2][16][16KB]
  float* G = (float*)(ws);   // aliases ins (dead after GEMM1)

  xscrub_kernel<<<128, 256, 0, stream>>>(xex);
  cast_concat_kernel<<<32768, 256, 0, stream>>>(Mf, DTf, Df, ins);
  cast_w_kernel<<<512, 256, 0, stream>>>(Wih0, w0b, 131072);
  cast_w_kernel<<<256, 256, 0, stream>>>(Wih1, w1b, 65536);

  // H = relu(ins @ W_ih0^T): M=65536 N=1024 K=1024 -> 256x4 = 1024 tiles
  gemm256_kernel<1, unsigned short><<<(65536 / 256) * (1024 / 256), 512, 0, stream>>>(
      ins, w0b, H, 65536, 1024, 1024);
  // G = H @ W_ih1^T: M=65536 N=512 K=1024 -> 256x2 = 512 tiles
  gemm256_kernel<0, float><<<(65536 / 256) * (512 / 256), 512, 0, stream>>>(
      H, w1b, G, 65536, 512, 1024);

  float* X = (float*)d_out;
  float* Y = X + 33554432;
  recurrence_tf<<<64, 256, 0, stream>>>(Whh1, x0, G, xex, X, Y);
}